// Round 19
// baseline (1165.109 us; speedup 1.0000x reference)
//
#include <hip/hip_runtime.h>
#include <math.h>

#define N_NODES 50000
#define N_EDGES 1600000
#define F_DIM 1024
#define D_DIM 256
#define B_IDS 16384

#define BROWS 1024            // rows per bucket
#define BKT 49                // buckets per graph (ceil(50000/1024))
#define NB3 (3 * BKT)         // 147
#define CHUNK 4096            // edges per partition block

typedef __attribute__((ext_vector_type(8))) short bf16x8;
typedef __attribute__((ext_vector_type(4))) float f32x4;

static inline size_t alignup(size_t x) { return (x + 255) & ~(size_t)255; }

__device__ inline unsigned short f2bf(float f) {
  unsigned u = __float_as_uint(f);
  u += 0x7fffu + ((u >> 16) & 1u);   // RNE (inputs are finite)
  return (unsigned short)(u >> 16);
}
__device__ inline float bf2f(unsigned short u) {
  return __uint_as_float(((unsigned)u) << 16);
}

// cheap 3-term split: hi = trunc16(a), lo = trunc16(a - hi); pair-packed bit ops.
__device__ inline void split_pair(float a, float b, unsigned& hi, unsigned& lo) {
  const unsigned ua = __float_as_uint(a), ub = __float_as_uint(b);
  hi = (ua >> 16) | (ub & 0xffff0000u);
  const float ra = a - __uint_as_float(ua & 0xffff0000u);
  const float rb = b - __uint_as_float(ub & 0xffff0000u);
  lo = (__float_as_uint(ra) >> 16) | (__float_as_uint(rb) & 0xffff0000u);
}
// 1-term: hi only (trunc), for branches with short error paths.
__device__ inline unsigned trunc_pair(float a, float b) {
  return (__float_as_uint(a) >> 16) | (__float_as_uint(b) & 0xffff0000u);
}

__device__ inline void glds16(const void* g, void* l) {
  __builtin_amdgcn_global_load_lds(
      (const __attribute__((address_space(1))) void*)g,
      (__attribute__((address_space(3))) void*)l, 16, 0, 0);
}

// ---- fused weight transpose + bf16 hi/lo split for all 6 weights ----
struct TrArgs {
  const float* W[6];
  unsigned short* Wh[6];
  unsigned short* Wl[6];
  int K[6];
};

__global__ __launch_bounds__(256) void tr_all_k(TrArgs a) {
  const int z = blockIdx.z;
  const int K = a.K[z];
  if (blockIdx.x * 64 >= K) return;
  const float* W = a.W[z];
  unsigned short* Wt_hi = a.Wh[z];
  unsigned short* Wt_lo = a.Wl[z];
  __shared__ float t[64][65];
  const int k0 = blockIdx.x * 64, n0 = blockIdx.y * 64;
  const int tid = threadIdx.x;
  const int rr = tid >> 4, c4 = (tid & 15) * 4;
#pragma unroll
  for (int q = 0; q < 4; ++q) {
    int row = q * 16 + rr;
    const float4 v = *reinterpret_cast<const float4*>(W + (size_t)(k0 + row) * 256 + n0 + c4);
    t[row][c4 + 0] = v.x; t[row][c4 + 1] = v.y; t[row][c4 + 2] = v.z; t[row][c4 + 3] = v.w;
  }
  __syncthreads();
#pragma unroll
  for (int q = 0; q < 4; ++q) {
    int n = q * 16 + rr;
    ushort4 oh, ol;
    float w0 = t[c4 + 0][n], w1 = t[c4 + 1][n], w2 = t[c4 + 2][n], w3 = t[c4 + 3][n];
    oh.x = f2bf(w0); ol.x = f2bf(w0 - bf2f(oh.x));
    oh.y = f2bf(w1); ol.y = f2bf(w1 - bf2f(oh.y));
    oh.z = f2bf(w2); ol.z = f2bf(w2 - bf2f(oh.z));
    oh.w = f2bf(w3); ol.w = f2bf(w3 - bf2f(oh.w));
    *reinterpret_cast<ushort4*>(Wt_hi + (size_t)(n0 + n) * K + k0 + c4) = oh;
    *reinterpret_cast<ushort4*>(Wt_lo + (size_t)(n0 + n) * K + k0 + c4) = ol;
  }
}

// =============== CSR build via 2-level bucket sort ===============

__global__ __launch_bounds__(256) void bcount_k(
    const int* __restrict__ r0, const int* __restrict__ r1, const int* __restrict__ r2,
    int* __restrict__ bcnt)
{
  __shared__ int h[NB3];
  const int t = threadIdx.x;
  for (int i = t; i < NB3; i += 256) h[i] = 0;
  __syncthreads();
  const long long cbase = (long long)blockIdx.x * CHUNK;
  const long long tot = 3LL * N_EDGES;
#pragma unroll
  for (int j = 0; j < 16; ++j) {
    long long idx = cbase + j * 256 + t;
    if (idx < tot) {
      int g = (int)(idx / N_EDGES);
      int e = (int)(idx - (long long)g * N_EDGES);
      int row = (g == 0 ? r0 : g == 1 ? r1 : r2)[e];
      atomicAdd(&h[g * BKT + (row >> 10)], 1);
    }
  }
  __syncthreads();
  for (int i = t; i < NB3; i += 256)
    if (h[i]) atomicAdd(&bcnt[i], h[i]);
}

__global__ void bscan_k(const int* __restrict__ bcnt, int* __restrict__ flatBase,
                        int* __restrict__ cursor) {
  __shared__ int c[NB3];
  const int t = threadIdx.x;
  if (t < NB3) c[t] = bcnt[t];
  __syncthreads();
  if (t < 3) {
    int acc = t * N_EDGES;
    for (int b = 0; b < BKT; ++b) {
      int i = t * BKT + b;
      int v = c[i];
      flatBase[i] = acc;
      cursor[i] = acc;
      acc += v;
    }
  }
  if (t == 0) flatBase[NB3] = 3 * N_EDGES;
}

__global__ __launch_bounds__(256) void bpart_k(
    const int* __restrict__ r0, const int* __restrict__ c0, const float* __restrict__ v0,
    const int* __restrict__ r1, const int* __restrict__ c1, const float* __restrict__ v1,
    const int* __restrict__ r2, const int* __restrict__ c2, const float* __restrict__ v2,
    int* __restrict__ cursor, int2* __restrict__ packed)
{
  __shared__ int hs[256];
  __shared__ int ls[NB3];
  __shared__ int cur[NB3];
  __shared__ int clm[NB3];
  __shared__ int2 stg[CHUNK];
  __shared__ int tgt[CHUNK];
  const int t = threadIdx.x;
  const long long cbase = (long long)blockIdx.x * CHUNK;
  const long long tot = 3LL * N_EDGES;
  hs[t] = 0;
  __syncthreads();
  int rows_[16], gbs_[16];
#pragma unroll
  for (int j = 0; j < 16; ++j) {
    long long idx = cbase + j * 256 + t;
    int gb = -1, row = 0;
    if (idx < tot) {
      int g = (int)(idx / N_EDGES);
      int e = (int)(idx - (long long)g * N_EDGES);
      row = (g == 0 ? r0 : g == 1 ? r1 : r2)[e];
      gb = g * BKT + (row >> 10);
      atomicAdd(&hs[gb], 1);
    }
    gbs_[j] = gb; rows_[j] = row;
  }
  __syncthreads();
  const int myh = hs[t];
  if (t < NB3) clm[t] = atomicAdd(&cursor[t], myh);
  for (int off = 1; off < 256; off <<= 1) {
    int v = (t >= off) ? hs[t - off] : 0;
    __syncthreads();
    hs[t] += v;
    __syncthreads();
  }
  const int excl = hs[t] - myh;
  if (t < NB3) { ls[t] = excl; cur[t] = excl; }
  __syncthreads();
#pragma unroll
  for (int j = 0; j < 16; ++j) {
    const int gb = gbs_[j];
    if (gb >= 0) {
      long long idx = cbase + j * 256 + t;
      int g = (int)(idx / N_EDGES);
      int e = (int)(idx - (long long)g * N_EDGES);
      int col = (g == 0 ? c0 : g == 1 ? c1 : c2)[e];
      float vv = (g == 0 ? v0 : g == 1 ? v1 : v2)[e];
      int slot = atomicAdd(&cur[gb], 1);
      stg[slot] = make_int2(rows_[j] | (col << 16), __float_as_int(vv));
      tgt[slot] = clm[gb] + (slot - ls[gb]);
    }
  }
  __syncthreads();
  const int cnt = (int)min((long long)CHUNK, tot - cbase);
  for (int i = t; i < cnt; i += 256) packed[tgt[i]] = stg[i];
}

__global__ __launch_bounds__(256) void bfinal_k(
    const int2* __restrict__ packed, const int* __restrict__ flatBase,
    int* __restrict__ row_ptr3, int2* __restrict__ cv3)
{
  __shared__ int hist[BROWS];
  __shared__ int part[256];
  const int gb = blockIdx.x;
  const int g = gb / BKT, b = gb % BKT;
  const int rb = b * BROWS;
  const int nrows = min(BROWS, N_NODES - rb);
  const int base = flatBase[gb];
  const int cnt = flatBase[gb + 1] - base;
  const int cvb = base - g * N_EDGES;
  const int t = threadIdx.x;
  for (int i = t; i < BROWS; i += 256) hist[i] = 0;
  __syncthreads();
  for (int i = t; i < cnt; i += 256) {
    int rc = packed[base + i].x;
    atomicAdd(&hist[(rc & 0xffff) - rb], 1);
  }
  __syncthreads();
  const int l0 = hist[4 * t], l1 = hist[4 * t + 1], l2 = hist[4 * t + 2], l3 = hist[4 * t + 3];
  const int s = l0 + l1 + l2 + l3;
  part[t] = s;
  __syncthreads();
  for (int off = 1; off < 256; off <<= 1) {
    int v = (t >= off) ? part[t - off] : 0;
    __syncthreads();
    part[t] += v;
    __syncthreads();
  }
  const int pexcl = part[t] - s;
  const int e0 = pexcl, e1 = e0 + l0, e2 = e1 + l1, e3 = e2 + l2;
  hist[4 * t] = e0; hist[4 * t + 1] = e1; hist[4 * t + 2] = e2; hist[4 * t + 3] = e3;
  int* rp = row_ptr3 + (size_t)g * (N_NODES + 1);
  if (4 * t + 0 < nrows) rp[rb + 4 * t + 0] = cvb + e0;
  if (4 * t + 1 < nrows) rp[rb + 4 * t + 1] = cvb + e1;
  if (4 * t + 2 < nrows) rp[rb + 4 * t + 2] = cvb + e2;
  if (4 * t + 3 < nrows) rp[rb + 4 * t + 3] = cvb + e3;
  if (rb + BROWS >= N_NODES && t == 0) rp[N_NODES] = N_EDGES;
  __syncthreads();
  for (int i = t; i < cnt; i += 256) {
    int2 p = packed[base + i];
    int row = p.x & 0xffff;
    int col = ((unsigned)p.x) >> 16;
    int pos = atomicAdd(&hist[row - rb], 1);
    cv3[base + pos] = make_int2(col, p.y);
  }
}

__global__ void flag_k(const int* __restrict__ ids, unsigned char* __restrict__ flag, int B) {
  int i = blockIdx.x * blockDim.x + threadIdx.x;
  if (i < B) flag[ids[i]] = 1;
}

// ---- spmm inner helper: 8-deep MLP gather loop (bf16 src) ----
__device__ inline void spmm_row(const int2* __restrict__ cv, int e0, int e1,
                                const unsigned short* __restrict__ srcb, int c0,
                                float& a0, float& a1, float& a2, float& a3)
{
  int e = e0;
  for (; e + 7 < e1; e += 8) {
    int2 p[8];
    ushort4 x[8];
#pragma unroll
    for (int j = 0; j < 8; ++j) p[j] = cv[e + j];
#pragma unroll
    for (int j = 0; j < 8; ++j)
      x[j] = *reinterpret_cast<const ushort4*>(srcb + (size_t)p[j].x * D_DIM + c0);
#pragma unroll
    for (int j = 0; j < 8; ++j) {
      const float v = __int_as_float(p[j].y);
      a0 = fmaf(v, bf2f(x[j].x), a0); a1 = fmaf(v, bf2f(x[j].y), a1);
      a2 = fmaf(v, bf2f(x[j].z), a2); a3 = fmaf(v, bf2f(x[j].w), a3);
    }
  }
  for (; e + 3 < e1; e += 4) {
    int2 p[4];
    ushort4 x[4];
#pragma unroll
    for (int j = 0; j < 4; ++j) p[j] = cv[e + j];
#pragma unroll
    for (int j = 0; j < 4; ++j)
      x[j] = *reinterpret_cast<const ushort4*>(srcb + (size_t)p[j].x * D_DIM + c0);
#pragma unroll
    for (int j = 0; j < 4; ++j) {
      const float v = __int_as_float(p[j].y);
      a0 = fmaf(v, bf2f(x[j].x), a0); a1 = fmaf(v, bf2f(x[j].y), a1);
      a2 = fmaf(v, bf2f(x[j].z), a2); a3 = fmaf(v, bf2f(x[j].w), a3);
    }
  }
  for (; e < e1; ++e) {
    int2 p = cv[e];
    float v = __int_as_float(p.y);
    const ushort4 x = *reinterpret_cast<const ushort4*>(srcb + (size_t)p.x * D_DIM + c0);
    a0 = fmaf(v, bf2f(x.x), a0); a1 = fmaf(v, bf2f(x.y), a1);
    a2 = fmaf(v, bf2f(x.z), a2); a3 = fmaf(v, bf2f(x.w), a3);
  }
}

// ---------------- SpMM: bf16 gather, f32 accumulate/out (+opt bf16 shadow) ----
__global__ __launch_bounds__(256) void spmm_k(
    const int* __restrict__ row_ptr, const int2* __restrict__ cv,
    const unsigned short* __restrict__ srcb, float* __restrict__ dst,
    unsigned short* __restrict__ dstb,
    const float* __restrict__ bias, int do_leaky,
    const unsigned char* __restrict__ flag, int n)
{
  int r = (blockIdx.x << 2) + (threadIdx.x >> 6);
  if (r >= n) return;
  if (flag && !flag[r]) return;
  const int lane = threadIdx.x & 63;
  const int c0 = lane << 2;
  int e0 = row_ptr[r], e1 = row_ptr[r + 1];
  float a0 = 0.f, a1 = 0.f, a2 = 0.f, a3 = 0.f;
  spmm_row(cv, e0, e1, srcb, c0, a0, a1, a2, a3);
  if (bias) {
    const float4 b = *reinterpret_cast<const float4*>(bias + c0);
    a0 += b.x; a1 += b.y; a2 += b.z; a3 += b.w;
  }
  if (do_leaky) {
    a0 = a0 > 0.f ? a0 : 0.01f * a0;
    a1 = a1 > 0.f ? a1 : 0.01f * a1;
    a2 = a2 > 0.f ? a2 : 0.01f * a2;
    a3 = a3 > 0.f ? a3 : 0.01f * a3;
  }
  *reinterpret_cast<float4*>(dst + (size_t)r * D_DIM + c0) =
      make_float4(a0, a1, a2, a3);
  if (dstb) {
    ushort4 o;
    o.x = f2bf(a0); o.y = f2bf(a1); o.z = f2bf(a2); o.w = f2bf(a3);
    *reinterpret_cast<ushort4*>(dstb + (size_t)r * D_DIM + c0) = o;
  }
}

// ---- fused rel+attr flagged spmm (z selects graph) ----
struct SP2 {
  const int* rp[2];
  const int2* cv[2];
  const unsigned short* src[2];
  float* dst[2];
  const float* bias[2];
};
__global__ __launch_bounds__(256) void spmm2_k(SP2 a, const unsigned char* __restrict__ flag) {
  const int z = blockIdx.y;
  int r = (blockIdx.x << 2) + (threadIdx.x >> 6);
  if (r >= N_NODES) return;
  if (!flag[r]) return;
  const unsigned short* srcb = a.src[z];
  const int lane = threadIdx.x & 63;
  const int c0 = lane << 2;
  int e0 = a.rp[z][r], e1 = a.rp[z][r + 1];
  const int2* cv = a.cv[z];
  float a0 = 0.f, a1 = 0.f, a2 = 0.f, a3 = 0.f;
  spmm_row(cv, e0, e1, srcb, c0, a0, a1, a2, a3);
  const float4 b = *reinterpret_cast<const float4*>(a.bias[z] + c0);
  a0 += b.x; a1 += b.y; a2 += b.z; a3 += b.w;
  a0 = a0 > 0.f ? a0 : 0.01f * a0;
  a1 = a1 > 0.f ? a1 : 0.01f * a1;
  a2 = a2 > 0.f ? a2 : 0.01f * a2;
  a3 = a3 > 0.f ? a3 : 0.01f * a3;
  *reinterpret_cast<float4*>(a.dst[z] + (size_t)r * D_DIM + c0) =
      make_float4(a0, a1, a2, a3);
}

// ---------------- fused 3-way big GEMM (K=1024, 128x256 tile, BK=64, bf16 out) ----
// z==2 (ent): 3-term split-precision. z<2 (rel/attr): 1-term truncated bf16.
// BK=64: two k-steps per staged chunk, processed SEQUENTIALLY with one ah/al
// register set (no extra live A-set -> no spill; r12/r13 failed by keeping two).
// Halves the barrier pairs (16 vs 32); ks1's A-load is covered by ks0's MFMAs.
// LDS 64KB: hi ks0 [0,16K) ks1 [16K,32K); lo ks0 [32K,48K) ks1 [48K,64K).
struct MM3 {
  const float* A[3];
  const unsigned short* Wh[3];
  const unsigned short* Wl[3];
  unsigned short* Cb[3];
};
__global__ __launch_bounds__(512, 4) void mm3_k(MM3 a) {
  constexpr int KT = F_DIM;
  const int z = blockIdx.y;
  const bool full = (z == 2);
  const float* __restrict__ Aptr = a.A[z];
  const unsigned short* __restrict__ Wt_hi = a.Wh[z];
  const unsigned short* __restrict__ Wt_lo = a.Wl[z];
  unsigned short* __restrict__ Cb = a.Cb[z];

  __shared__ __align__(16) unsigned char smem[65536];
  const int tid = threadIdx.x;
  const int wid = tid >> 6, lane = tid & 63;
  const int wm = wid & 3, wn = wid >> 2;       // 4 (M) x 2 (N) waves
  const int bm = blockIdx.x * 128;
  const int l15 = lane & 15, lk = lane >> 4;

  int mrow[2];
  const float* arow[2];
#pragma unroll
  for (int mi = 0; mi < 2; ++mi) {
    int m = bm + wm * 32 + mi * 16 + l15;
    mrow[mi] = m;
    arow[mi] = Aptr + (size_t)((m < N_NODES) ? m : 0) * KT;
  }

  const int s1 = tid, s2 = tid + 512;
  const size_t go1 = (size_t)(s1 >> 2) * KT + ((((s1 & 3) - ((s1 >> 3) & 3)) & 3) << 3);
  const size_t go2 = (size_t)(s2 >> 2) * KT + ((((s2 & 3) - ((s2 >> 3) & 3)) & 3) << 3);

  f32x4 acc[2][8] = {};
  bf16x8 ah[2], al[2];

  for (int kc = 0; kc < KT / 64; ++kc) {
    const int kk = kc * 64;
    __syncthreads();   // previous chunk's reads complete before overwrite
    glds16(Wt_hi + go1 + kk,      smem + s1 * 16);
    glds16(Wt_hi + go2 + kk,      smem + s2 * 16);
    glds16(Wt_hi + go1 + kk + 32, smem + 16384 + s1 * 16);
    glds16(Wt_hi + go2 + kk + 32, smem + 16384 + s2 * 16);
    if (full) {
      glds16(Wt_lo + go1 + kk,      smem + 32768 + s1 * 16);
      glds16(Wt_lo + go2 + kk,      smem + 32768 + s2 * 16);
      glds16(Wt_lo + go1 + kk + 32, smem + 49152 + s1 * 16);
      glds16(Wt_lo + go2 + kk + 32, smem + 49152 + s2 * 16);
    }
    // A fragments for ks0 (overlap staging latency)
#pragma unroll
    for (int mi = 0; mi < 2; ++mi) {
      uint4 th = {0, 0, 0, 0}, tl = {0, 0, 0, 0};
      if (mrow[mi] < N_NODES) {
        const float* p = arow[mi] + kk + lk * 8;
        const float4 x = *reinterpret_cast<const float4*>(p);
        const float4 y = *reinterpret_cast<const float4*>(p + 4);
        if (full) {
          split_pair(x.x, x.y, th.x, tl.x);
          split_pair(x.z, x.w, th.y, tl.y);
          split_pair(y.x, y.y, th.z, tl.z);
          split_pair(y.z, y.w, th.w, tl.w);
        } else {
          th.x = trunc_pair(x.x, x.y);
          th.y = trunc_pair(x.z, x.w);
          th.z = trunc_pair(y.x, y.y);
          th.w = trunc_pair(y.z, y.w);
        }
      }
      ah[mi] = *reinterpret_cast<bf16x8*>(&th);
      al[mi] = *reinterpret_cast<bf16x8*>(&tl);
    }
    __syncthreads();   // staging drained (vmcnt(0)+barrier)

#pragma unroll
    for (int ks = 0; ks < 2; ++ks) {
      if (ks == 1) {
        // A fragments for ks1 (covered by ks0's MFMAs already issued)
#pragma unroll
        for (int mi = 0; mi < 2; ++mi) {
          uint4 th = {0, 0, 0, 0}, tl = {0, 0, 0, 0};
          if (mrow[mi] < N_NODES) {
            const float* p = arow[mi] + kk + 32 + lk * 8;
            const float4 x = *reinterpret_cast<const float4*>(p);
            const float4 y = *reinterpret_cast<const float4*>(p + 4);
            if (full) {
              split_pair(x.x, x.y, th.x, tl.x);
              split_pair(x.z, x.w, th.y, tl.y);
              split_pair(y.x, y.y, th.z, tl.z);
              split_pair(y.z, y.w, th.w, tl.w);
            } else {
              th.x = trunc_pair(x.x, x.y);
              th.y = trunc_pair(x.z, x.w);
              th.z = trunc_pair(y.x, y.y);
              th.w = trunc_pair(y.z, y.w);
            }
          }
          ah[mi] = *reinterpret_cast<bf16x8*>(&th);
          al[mi] = *reinterpret_cast<bf16x8*>(&tl);
        }
      }
      const int rbase = ks * 16384;
#pragma unroll
      for (int f = 0; f < 8; ++f) {
        const int n = wn * 128 + f * 16 + l15;
        const int boff = rbase + n * 64 + (((lk + (n >> 1)) & 3) << 4);
        const bf16x8 bh = *reinterpret_cast<const bf16x8*>(smem + boff);
#pragma unroll
        for (int mi = 0; mi < 2; ++mi)
          acc[mi][f] = __builtin_amdgcn_mfma_f32_16x16x32_bf16(ah[mi], bh, acc[mi][f], 0, 0, 0);
        if (full) {
          const bf16x8 bl = *reinterpret_cast<const bf16x8*>(smem + 32768 + boff);
#pragma unroll
          for (int mi = 0; mi < 2; ++mi) {
            acc[mi][f] = __builtin_amdgcn_mfma_f32_16x16x32_bf16(al[mi], bh, acc[mi][f], 0, 0, 0);
            acc[mi][f] = __builtin_amdgcn_mfma_f32_16x16x32_bf16(ah[mi], bl, acc[mi][f], 0, 0, 0);
          }
        }
      }
    }
  }

#pragma unroll
  for (int mi = 0; mi < 2; ++mi) {
    const int rbase = bm + wm * 32 + mi * 16 + lk * 4;
#pragma unroll
    for (int f = 0; f < 8; ++f) {
      const int col = wn * 128 + f * 16 + l15;
#pragma unroll
      for (int r = 0; r < 4; ++r) {
        const int row = rbase + r;
        if (row >= N_NODES) continue;
        Cb[(size_t)row * D_DIM + col] = f2bf(acc[mi][f][r]);
      }
    }
  }
}

// ---------------- col-split MFMA GEMM (64 rows x 128 cols, BK=64) ----------------
// NOT safe for in-place C==A. Used for the ids-GEMMs (lit, nxt3, h3).
template<int KT, int MODE>
__global__ __launch_bounds__(256, 4) void mm_k(
    const float* __restrict__ Aptr,
    const unsigned short* __restrict__ Wt_hi,
    const unsigned short* __restrict__ Wt_lo,
    const float* __restrict__ bias,
    float* __restrict__ C, int ldc, int ccol0, int M,
    const int* __restrict__ rowidx,
    const float* __restrict__ nxt, const float* __restrict__ hin,
    unsigned short* __restrict__ Cb)
{
  __shared__ __align__(16) unsigned char smem[32768];
  const int tid = threadIdx.x;
  const int wid = tid >> 6, lane = tid & 63;
  const int wm = wid & 1, wn = wid >> 1;
  const int bm = blockIdx.y * 64;
  const int bn0 = blockIdx.x * 128;
  const int l15 = lane & 15, lk = lane >> 4;

  int mrow[2];
  const float* arow[2];
#pragma unroll
  for (int mi = 0; mi < 2; ++mi) {
    int m = bm + wm * 32 + mi * 16 + l15;
    mrow[mi] = m;
    int sr = (m < M) ? (rowidx ? rowidx[m] : m) : 0;
    arow[mi] = Aptr + (size_t)sr * KT;
  }

  const int st_n = tid >> 2;
  const int st_seg = ((tid & 3) - ((tid >> 3) & 3)) & 3;
  const size_t goA = (size_t)(bn0 + st_n) * KT + st_seg * 8;
  const size_t goB = goA + (size_t)64 * KT;
  const unsigned ldA = tid * 16, ldB = tid * 16 + 4096;

  f32x4 acc[2][4] = {};
  for (int kc = 0; kc < KT / 64; ++kc) {
    const int kk = kc * 64;
    __syncthreads();
    glds16(Wt_hi + goA + kk,      smem + ldA);
    glds16(Wt_hi + goB + kk,      smem + ldB);
    glds16(Wt_hi + goA + kk + 32, smem + 8192 + ldA);
    glds16(Wt_hi + goB + kk + 32, smem + 8192 + ldB);
    glds16(Wt_lo + goA + kk,      smem + 16384 + ldA);
    glds16(Wt_lo + goB + kk,      smem + 16384 + ldB);
    glds16(Wt_lo + goA + kk + 32, smem + 24576 + ldA);
    glds16(Wt_lo + goB + kk + 32, smem + 24576 + ldB);
    bf16x8 ah[2][2], al[2][2];
#pragma unroll
    for (int ks = 0; ks < 2; ++ks) {
      const int ka = kk + ks * 32 + lk * 8;
#pragma unroll
      for (int mi = 0; mi < 2; ++mi) {
        uint4 th = {0, 0, 0, 0}, tl = {0, 0, 0, 0};
        if (mrow[mi] < M) {
          const float* p = arow[mi] + ka;
          const float4 x = *reinterpret_cast<const float4*>(p);
          const float4 y = *reinterpret_cast<const float4*>(p + 4);
          split_pair(x.x, x.y, th.x, tl.x);
          split_pair(x.z, x.w, th.y, tl.y);
          split_pair(y.x, y.y, th.z, tl.z);
          split_pair(y.z, y.w, th.w, tl.w);
        }
        ah[ks][mi] = *reinterpret_cast<bf16x8*>(&th);
        al[ks][mi] = *reinterpret_cast<bf16x8*>(&tl);
      }
    }
    __syncthreads();
#pragma unroll
    for (int ks = 0; ks < 2; ++ks) {
#pragma unroll
      for (int f = 0; f < 4; ++f) {
        const int n = wn * 64 + f * 16 + l15;
        const int boff = ks * 8192 + n * 64 + (((lk + (n >> 1)) & 3) << 4);
        const bf16x8 bh = *reinterpret_cast<const bf16x8*>(smem + boff);
        const bf16x8 bl = *reinterpret_cast<const bf16x8*>(smem + 16384 + boff);
#pragma unroll
        for (int mi = 0; mi < 2; ++mi) {
          acc[mi][f] = __builtin_amdgcn_mfma_f32_16x16x32_bf16(ah[ks][mi], bh, acc[mi][f], 0, 0, 0);
          acc[mi][f] = __builtin_amdgcn_mfma_f32_16x16x32_bf16(al[ks][mi], bh, acc[mi][f], 0, 0, 0);
          acc[mi][f] = __builtin_amdgcn_mfma_f32_16x16x32_bf16(ah[ks][mi], bl, acc[mi][f], 0, 0, 0);
        }
      }
    }
  }

  __syncthreads();

#pragma unroll
  for (int mi = 0; mi < 2; ++mi) {
    const int rbase = bm + wm * 32 + mi * 16 + lk * 4;
    int hsrc[4];
    if (MODE == 2) {
#pragma unroll
      for (int r = 0; r < 4; ++r) {
        const int row = rbase + r;
        hsrc[r] = (rowidx && row < M) ? rowidx[row] : row;
      }
    }
#pragma unroll
    for (int f = 0; f < 4; ++f) {
      const int col = bn0 + wn * 64 + f * 16 + l15;
      const float bc = bias ? bias[col] : 0.f;
#pragma unroll
      for (int r = 0; r < 4; ++r) {
        const int row = rbase + r;
        if (row >= M) continue;
        float v = acc[mi][f][r] + bc;
        if (MODE == 1) v = v > 0.f ? v : 0.01f * v;
        if (MODE == 2) {
          const float g = 1.f / (1.f + __expf(-v));
          const float nv = nxt[(size_t)row * D_DIM + col];
          const float hv = hin[(size_t)hsrc[r] * D_DIM + col];
          v = g * nv + (1.f - g) * hv;
        }
        C[(size_t)row * ldc + ccol0 + col] = v;
        if (Cb) Cb[(size_t)row * D_DIM + col] = f2bf(v);
      }
    }
  }
}

// ---------------- full-width MFMA GEMM (128 rows x 256 cols, 512 thr) -------
// Safe for in-place C==A. Used for the two in-place D-GEMMs (nxt2, h2).
template<int KT, int MODE>
__global__ __launch_bounds__(512, 4) void mmw_k(
    const float* __restrict__ Aptr,
    const unsigned short* __restrict__ Wt_hi,
    const unsigned short* __restrict__ Wt_lo,
    const float* __restrict__ bias,
    float* __restrict__ C, int ldc, int ccol0, int M,
    const int* __restrict__ rowidx,
    const float* __restrict__ nxt, const float* __restrict__ hin,
    unsigned short* __restrict__ Cb)
{
  __shared__ __align__(16) unsigned char smem[32768];
  const int tid = threadIdx.x;
  const int wid = tid >> 6, lane = tid & 63;
  const int wm = wid & 3, wn = wid >> 2;
  const int bm = blockIdx.x * 128;
  const int l15 = lane & 15, lk = lane >> 4;

  int mrow[2];
  const float* arow[2];
#pragma unroll
  for (int mi = 0; mi < 2; ++mi) {
    int m = bm + wm * 32 + mi * 16 + l15;
    mrow[mi] = m;
    int sr = (m < M) ? (rowidx ? rowidx[m] : m) : 0;
    arow[mi] = Aptr + (size_t)sr * KT;
  }

  const int s1 = tid, s2 = tid + 512;
  const size_t go1 = (size_t)(s1 >> 2) * KT + ((((s1 & 3) - ((s1 >> 3) & 3)) & 3) << 3);
  const size_t go2 = (size_t)(s2 >> 2) * KT + ((((s2 & 3) - ((s2 >> 3) & 3)) & 3) << 3);

  f32x4 acc[2][8] = {};
  for (int kc = 0; kc < KT / 32; ++kc) {
    const int kk = kc * 32;
    __syncthreads();
    glds16(Wt_hi + go1 + kk, smem + s1 * 16);
    glds16(Wt_hi + go2 + kk, smem + s2 * 16);
    glds16(Wt_lo + go1 + kk, smem + 16384 + s1 * 16);
    glds16(Wt_lo + go2 + kk, smem + 16384 + s2 * 16);
    const int ka = kk + lk * 8;
    bf16x8 ah[2], al[2];
#pragma unroll
    for (int mi = 0; mi < 2; ++mi) {
      uint4 th = {0, 0, 0, 0}, tl = {0, 0, 0, 0};
      if (mrow[mi] < M) {
        const float* p = arow[mi] + ka;
        const float4 x = *reinterpret_cast<const float4*>(p);
        const float4 y = *reinterpret_cast<const float4*>(p + 4);
        split_pair(x.x, x.y, th.x, tl.x);
        split_pair(x.z, x.w, th.y, tl.y);
        split_pair(y.x, y.y, th.z, tl.z);
        split_pair(y.z, y.w, th.w, tl.w);
      }
      ah[mi] = *reinterpret_cast<bf16x8*>(&th);
      al[mi] = *reinterpret_cast<bf16x8*>(&tl);
    }
    __syncthreads();
#pragma unroll
    for (int f = 0; f < 8; ++f) {
      const int n = wn * 128 + f * 16 + l15;
      const int boff = n * 64 + (((lk + (n >> 1)) & 3) << 4);
      const bf16x8 bh = *reinterpret_cast<const bf16x8*>(smem + boff);
      const bf16x8 bl = *reinterpret_cast<const bf16x8*>(smem + 16384 + boff);
#pragma unroll
      for (int mi = 0; mi < 2; ++mi) {
        acc[mi][f] = __builtin_amdgcn_mfma_f32_16x16x32_bf16(ah[mi], bh, acc[mi][f], 0, 0, 0);
        acc[mi][f] = __builtin_amdgcn_mfma_f32_16x16x32_bf16(al[mi], bh, acc[mi][f], 0, 0, 0);
        acc[mi][f] = __builtin_amdgcn_mfma_f32_16x16x32_bf16(ah[mi], bl, acc[mi][f], 0, 0, 0);
      }
    }
  }

  __syncthreads();   // in-place safety: all A reads in block done before writes

#pragma unroll
  for (int mi = 0; mi < 2; ++mi) {
    const int rbase = bm + wm * 32 + mi * 16 + lk * 4;
    int hsrc[4];
    if (MODE == 2) {
#pragma unroll
      for (int r = 0; r < 4; ++r) {
        const int row = rbase + r;
        hsrc[r] = (rowidx && row < M) ? rowidx[row] : row;
      }
    }
#pragma unroll
    for (int f = 0; f < 8; ++f) {
      const int col = wn * 128 + f * 16 + l15;
      const float bc = bias ? bias[col] : 0.f;
#pragma unroll
      for (int r = 0; r < 4; ++r) {
        const int row = rbase + r;
        if (row >= M) continue;
        float v = acc[mi][f][r] + bc;
        if (MODE == 1) v = v > 0.f ? v : 0.01f * v;
        if (MODE == 2) {
          const float g = 1.f / (1.f + __expf(-v));
          const float nv = nxt[(size_t)row * D_DIM + col];
          const float hv = hin[(size_t)hsrc[r] * D_DIM + col];
          v = g * nv + (1.f - g) * hv;
        }
        C[(size_t)row * ldc + ccol0 + col] = v;
        if (Cb) Cb[(size_t)row * D_DIM + col] = f2bf(v);
      }
    }
  }
}

// ---------------- row gathers ----------------
struct GA2 { const float* src[2]; int col0[2]; };
__global__ __launch_bounds__(256) void gather2_k(GA2 a, const int* __restrict__ ids,
                                                 float* __restrict__ dst)
{
  const int z = blockIdx.y;
  int i = (blockIdx.x << 2) + (threadIdx.x >> 6);
  if (i >= B_IDS) return;
  const int lane = threadIdx.x & 63;
  const int c0 = lane << 2;
  const float4 v = *reinterpret_cast<const float4*>(a.src[z] + (size_t)ids[i] * D_DIM + c0);
  *reinterpret_cast<float4*>(dst + (size_t)i * 1024 + a.col0[z] + c0) = v;
}

// ---------------- launch ----------------
extern "C" void kernel_launch(void* const* d_in, const int* in_sizes, int n_in,
                              void* d_out, int out_size, void* d_ws, size_t ws_size,
                              hipStream_t stream)
{
  const float* ent_lit = (const float*)d_in[0];
  const float* rel_lit = (const float*)d_in[1];
  const float* attr_lit = (const float*)d_in[2];
  const float* ent_val = (const float*)d_in[3];
  const float* rel_val = (const float*)d_in[4];
  const float* attr_val = (const float*)d_in[5];
  const float* W_ent = (const float*)d_in[6];
  const float* b_ent = (const float*)d_in[7];
  const float* W_rel = (const float*)d_in[8];
  const float* b_rel = (const float*)d_in[9];
  const float* W_attr = (const float*)d_in[10];
  const float* b_attr = (const float*)d_in[11];
  const float* W_x = (const float*)d_in[12];
  const float* b_x = (const float*)d_in[13];
  const float* W_lit = (const float*)d_in[14];
  const float* b_lit = (const float*)d_in[15];
  const float* W_gate = (const float*)d_in[16];
  const float* b_gate = (const float*)d_in[17];
  const int* ent_row = (const int*)d_in[18];
  const int* ent_col = (const int*)d_in[19];
  const int* rel_row = (const int*)d_in[20];
  const int* rel_col = (const int*)d_in[21];
  const int* attr_row = (const int*)d_in[22];
  const int* attr_col = (const int*)d_in[23];
  const int* ent_ids = (const int*)d_in[24];
  float* out = (float*)d_out;

  char* p = (char*)d_ws;
  const size_t bufsz = alignup((size_t)N_NODES * D_DIM * 4);
  const size_t bufszb = alignup((size_t)N_NODES * D_DIM * 2);
  const size_t wsz_f = alignup((size_t)F_DIM * D_DIM * 2);
  const size_t wsz_d = alignup((size_t)D_DIM * D_DIM * 2);
  float* B0 = (float*)p; p += bufsz;
  float* B1 = (float*)p; p += bufsz;
  unsigned short* Bb0 = (unsigned short*)p; p += bufszb;  // rel GEMM out -> h1 shadow
  unsigned short* Bb1 = (unsigned short*)p; p += bufszb;  // attr GEMM out -> h2 shadow
  unsigned short* Bb2 = (unsigned short*)p; p += bufszb;  // ent GEMM out -> (aliased by P)
  float* P = (float*)Bb2;  // Bb2 dead after h1 spmm; P (16.8MB) fits in Bb2 (25.6MB)
  unsigned short* Wh_ent = (unsigned short*)p; p += wsz_f;
  unsigned short* Wl_ent = (unsigned short*)p; p += wsz_f;
  unsigned short* Wh_rel = (unsigned short*)p; p += wsz_f;
  unsigned short* Wl_rel = (unsigned short*)p; p += wsz_f;
  unsigned short* Wh_attr = (unsigned short*)p; p += wsz_f;
  unsigned short* Wl_attr = (unsigned short*)p; p += wsz_f;
  unsigned short* Wh_lit = (unsigned short*)p; p += wsz_f;
  unsigned short* Wl_lit = (unsigned short*)p; p += wsz_f;
  unsigned short* Wh_x = (unsigned short*)p; p += wsz_d;
  unsigned short* Wl_x = (unsigned short*)p; p += wsz_d;
  unsigned short* Wh_gate = (unsigned short*)p; p += wsz_d;
  unsigned short* Wl_gate = (unsigned short*)p; p += wsz_d;
  int* row_ptr3 = (int*)p; p += alignup((size_t)3 * (N_NODES + 1) * 4);
  int* bcnt = (int*)p; p += alignup((size_t)NB3 * 4);
  int* flatBase = (int*)p; p += alignup((size_t)(NB3 + 1) * 4);
  int* cursor = (int*)p; p += alignup((size_t)NB3 * 4);
  unsigned char* flags = (unsigned char*)p; p += alignup((size_t)N_NODES);
  int2* cv3 = (int2*)p; p += alignup((size_t)3 * N_EDGES * 8);
  if ((size_t)(p - (char*)d_ws) > ws_size) return;

  // packed edge buffer aliases B0 (first real write to B0 is after bfinal)
  int2* packed = (int2*)B0;

  const int* rp_ent = row_ptr3;
  const int* rp_rel = row_ptr3 + (N_NODES + 1);
  const int* rp_attr = row_ptr3 + 2 * (N_NODES + 1);
  const int2* cv_ent = cv3;
  const int2* cv_rel = cv3 + (size_t)N_EDGES;
  const int2* cv_attr = cv3 + (size_t)2 * N_EDGES;

  dim3 blk(256), blk512(512);
  const int nchunks = (int)((3LL * N_EDGES + CHUNK - 1) / CHUNK);
  dim3 g_spmm((N_NODES + 3) / 4);
  dim3 g_spmm2((N_NODES + 3) / 4, 2);
  dim3 g_gather2((B_IDS + 3) / 4, 2);
  dim3 g_mm3((N_NODES + 127) / 128, 3);
  dim3 g_mm_ids(2, B_IDS / 64);
  dim3 g_mmw_big((N_NODES + 127) / 128);

  // weights -> bf16 hi/lo transposed (one fused launch)
  TrArgs ta;
  ta.W[0] = W_ent;  ta.Wh[0] = Wh_ent;  ta.Wl[0] = Wl_ent;  ta.K[0] = F_DIM;
  ta.W[1] = W_rel;  ta.Wh[1] = Wh_rel;  ta.Wl[1] = Wl_rel;  ta.K[1] = F_DIM;
  ta.W[2] = W_attr; ta.Wh[2] = Wh_attr; ta.Wl[2] = Wl_attr; ta.K[2] = F_DIM;
  ta.W[3] = W_lit;  ta.Wh[3] = Wh_lit;  ta.Wl[3] = Wl_lit;  ta.K[3] = F_DIM;
  ta.W[4] = W_x;    ta.Wh[4] = Wh_x;    ta.Wl[4] = Wl_x;    ta.K[4] = D_DIM;
  ta.W[5] = W_gate; ta.Wh[5] = Wh_gate; ta.Wl[5] = Wl_gate; ta.K[5] = D_DIM;
  tr_all_k<<<dim3(F_DIM / 64, 4, 6), blk, 0, stream>>>(ta);

  // CSR build (bucket sort)
  hipMemsetAsync(bcnt, 0, NB3 * sizeof(int), stream);
  bcount_k<<<dim3(nchunks), blk, 0, stream>>>(ent_row, rel_row, attr_row, bcnt);
  bscan_k<<<dim3(1), blk, 0, stream>>>(bcnt, flatBase, cursor);
  bpart_k<<<dim3(nchunks), blk, 0, stream>>>(ent_row, ent_col, ent_val,
                                             rel_row, rel_col, rel_val,
                                             attr_row, attr_col, attr_val,
                                             cursor, packed);
  bfinal_k<<<dim3(NB3), blk, 0, stream>>>(packed, flatBase, row_ptr3, cv3);

  // flags for row restriction (rows observed via ent_ids)
  hipMemsetAsync(flags, 0, N_NODES, stream);
  flag_k<<<dim3(B_IDS / 256), blk, 0, stream>>>(ent_ids, flags, B_IDS);

  // ----- fused big GEMMs: Bb0 = rel_lit@W_rel, Bb1 = attr_lit@W_attr, Bb2 = ent_lit@W_ent
  MM3 m3;
  m3.A[0] = rel_lit;  m3.Wh[0] = Wh_rel;  m3.Wl[0] = Wl_rel;  m3.Cb[0] = Bb0;
  m3.A[1] = attr_lit; m3.Wh[1] = Wh_attr; m3.Wl[1] = Wl_attr; m3.Cb[1] = Bb1;
  m3.A[2] = ent_lit;  m3.Wh[2] = Wh_ent;  m3.Wl[2] = Wl_ent;  m3.Cb[2] = Bb2;
  mm3_k<<<g_mm3, blk512, 0, stream>>>(m3);

  // ----- fused rel+attr flagged spmm: rel->B1, attr->B0
  SP2 s2;
  s2.rp[0] = rp_rel;  s2.cv[0] = cv_rel;  s2.src[0] = Bb0; s2.dst[0] = B1; s2.bias[0] = b_rel;
  s2.rp[1] = rp_attr; s2.cv[1] = cv_attr; s2.src[1] = Bb1; s2.dst[1] = B0; s2.bias[1] = b_attr;
  spmm2_k<<<g_spmm2, blk, 0, stream>>>(s2, flags);

  // ----- fused gathers: B1 -> out[:,512:768], B0 -> out[:,768:1024]
  GA2 ga;
  ga.src[0] = B1; ga.col0[0] = 512;
  ga.src[1] = B0; ga.col0[1] = 768;
  gather2_k<<<g_gather2, blk, 0, stream>>>(ga, ent_ids, out);

  // ----- ent literals -> out[:,0:256]
  mm_k<F_DIM, 0><<<g_mm_ids, blk, 0, stream>>>(ent_lit, Wh_lit, Wl_lit, b_lit, out, 1024, 0,
                                               B_IDS, ent_ids, nullptr, nullptr, nullptr);

  // ----- ent n-hop -----
  // h1 = leaky(spmm(Bb2) + b_ent): f32 -> B1, bf16 shadow -> Bb0 (rel shadow dead)
  spmm_k<<<g_spmm, blk, 0, stream>>>(rp_ent, cv_ent, Bb2, B1, Bb0, b_ent, 1, nullptr, N_NODES);
  // hop 2: s2 = spmm(h1 shadow) -> B0 (f32 only)
  spmm_k<<<g_spmm, blk, 0, stream>>>(rp_ent, cv_ent, Bb0, B0, nullptr, nullptr, 0, nullptr, N_NODES);
  // in-place D-GEMMs use the full-width kernel
  mmw_k<D_DIM, 1><<<g_mmw_big, blk512, 0, stream>>>(B0, Wh_x, Wl_x, b_x, B0, D_DIM, 0,
                                                    N_NODES, nullptr, nullptr, nullptr, nullptr); // nxt2=B0
  mmw_k<D_DIM, 2><<<g_mmw_big, blk512, 0, stream>>>(B1, Wh_gate, Wl_gate, b_gate, B1, D_DIM, 0,
                                                    N_NODES, nullptr, B0, B1, Bb1);               // h2=B1(+Bb1)
  // hop 3 (flagged): s3 = spmm(h2 shadow) -> B0
  spmm_k<<<g_spmm, blk, 0, stream>>>(rp_ent, cv_ent, Bb1, B0, nullptr, nullptr, 0, flags, N_NODES);
  mm_k<D_DIM, 1><<<g_mm_ids, blk, 0, stream>>>(B0, Wh_x, Wl_x, b_x, P, D_DIM, 0,
                                               B_IDS, ent_ids, nullptr, nullptr, nullptr);   // nxt3 (P aliases Bb2)
  mm_k<D_DIM, 2><<<g_mm_ids, blk, 0, stream>>>(B1, Wh_gate, Wl_gate, b_gate, out, 1024, 256,
                                               B_IDS, ent_ids, P, B1, nullptr);              // -> out[:,256:512]
}

// Round 20
// 1143.901 us; speedup vs baseline: 1.0185x; 1.0185x over previous
//
#include <hip/hip_runtime.h>
#include <math.h>

#define N_NODES 50000
#define N_EDGES 1600000
#define F_DIM 1024
#define D_DIM 256
#define B_IDS 16384

#define BROWS 1024            // rows per bucket
#define BKT 49                // buckets per graph (ceil(50000/1024))
#define NB3 (3 * BKT)         // 147
#define CHUNK 4096            // edges per partition block

typedef __attribute__((ext_vector_type(8))) short bf16x8;
typedef __attribute__((ext_vector_type(4))) float f32x4;

static inline size_t alignup(size_t x) { return (x + 255) & ~(size_t)255; }

__device__ inline unsigned short f2bf(float f) {
  unsigned u = __float_as_uint(f);
  u += 0x7fffu + ((u >> 16) & 1u);   // RNE (inputs are finite)
  return (unsigned short)(u >> 16);
}
__device__ inline float bf2f(unsigned short u) {
  return __uint_as_float(((unsigned)u) << 16);
}

// cheap 3-term split: hi = trunc16(a), lo = trunc16(a - hi); pair-packed bit ops.
__device__ inline void split_pair(float a, float b, unsigned& hi, unsigned& lo) {
  const unsigned ua = __float_as_uint(a), ub = __float_as_uint(b);
  hi = (ua >> 16) | (ub & 0xffff0000u);
  const float ra = a - __uint_as_float(ua & 0xffff0000u);
  const float rb = b - __uint_as_float(ub & 0xffff0000u);
  lo = (__float_as_uint(ra) >> 16) | (__float_as_uint(rb) & 0xffff0000u);
}
// 1-term: hi only (trunc), for branches with short error paths.
__device__ inline unsigned trunc_pair(float a, float b) {
  return (__float_as_uint(a) >> 16) | (__float_as_uint(b) & 0xffff0000u);
}

__device__ inline void glds16(const void* g, void* l) {
  __builtin_amdgcn_global_load_lds(
      (const __attribute__((address_space(1))) void*)g,
      (__attribute__((address_space(3))) void*)l, 16, 0, 0);
}

// ---- fused weight transpose + bf16 hi/lo split for all 6 weights ----
struct TrArgs {
  const float* W[6];
  unsigned short* Wh[6];
  unsigned short* Wl[6];
  int K[6];
};

__global__ __launch_bounds__(256) void tr_all_k(TrArgs a) {
  const int z = blockIdx.z;
  const int K = a.K[z];
  if (blockIdx.x * 64 >= K) return;
  const float* W = a.W[z];
  unsigned short* Wt_hi = a.Wh[z];
  unsigned short* Wt_lo = a.Wl[z];
  __shared__ float t[64][65];
  const int k0 = blockIdx.x * 64, n0 = blockIdx.y * 64;
  const int tid = threadIdx.x;
  const int rr = tid >> 4, c4 = (tid & 15) * 4;
#pragma unroll
  for (int q = 0; q < 4; ++q) {
    int row = q * 16 + rr;
    const float4 v = *reinterpret_cast<const float4*>(W + (size_t)(k0 + row) * 256 + n0 + c4);
    t[row][c4 + 0] = v.x; t[row][c4 + 1] = v.y; t[row][c4 + 2] = v.z; t[row][c4 + 3] = v.w;
  }
  __syncthreads();
#pragma unroll
  for (int q = 0; q < 4; ++q) {
    int n = q * 16 + rr;
    ushort4 oh, ol;
    float w0 = t[c4 + 0][n], w1 = t[c4 + 1][n], w2 = t[c4 + 2][n], w3 = t[c4 + 3][n];
    oh.x = f2bf(w0); ol.x = f2bf(w0 - bf2f(oh.x));
    oh.y = f2bf(w1); ol.y = f2bf(w1 - bf2f(oh.y));
    oh.z = f2bf(w2); ol.z = f2bf(w2 - bf2f(oh.z));
    oh.w = f2bf(w3); ol.w = f2bf(w3 - bf2f(oh.w));
    *reinterpret_cast<ushort4*>(Wt_hi + (size_t)(n0 + n) * K + k0 + c4) = oh;
    *reinterpret_cast<ushort4*>(Wt_lo + (size_t)(n0 + n) * K + k0 + c4) = ol;
  }
}

// =============== CSR build via 2-level bucket sort ===============

__global__ __launch_bounds__(256) void bcount_k(
    const int* __restrict__ r0, const int* __restrict__ r1, const int* __restrict__ r2,
    int* __restrict__ bcnt)
{
  __shared__ int h[NB3];
  const int t = threadIdx.x;
  for (int i = t; i < NB3; i += 256) h[i] = 0;
  __syncthreads();
  const long long cbase = (long long)blockIdx.x * CHUNK;
  const long long tot = 3LL * N_EDGES;
#pragma unroll
  for (int j = 0; j < 16; ++j) {
    long long idx = cbase + j * 256 + t;
    if (idx < tot) {
      int g = (int)(idx / N_EDGES);
      int e = (int)(idx - (long long)g * N_EDGES);
      int row = (g == 0 ? r0 : g == 1 ? r1 : r2)[e];
      atomicAdd(&h[g * BKT + (row >> 10)], 1);
    }
  }
  __syncthreads();
  for (int i = t; i < NB3; i += 256)
    if (h[i]) atomicAdd(&bcnt[i], h[i]);
}

__global__ void bscan_k(const int* __restrict__ bcnt, int* __restrict__ flatBase,
                        int* __restrict__ cursor) {
  __shared__ int c[NB3];
  const int t = threadIdx.x;
  if (t < NB3) c[t] = bcnt[t];
  __syncthreads();
  if (t < 3) {
    int acc = t * N_EDGES;
    for (int b = 0; b < BKT; ++b) {
      int i = t * BKT + b;
      int v = c[i];
      flatBase[i] = acc;
      cursor[i] = acc;
      acc += v;
    }
  }
  if (t == 0) flatBase[NB3] = 3 * N_EDGES;
}

__global__ __launch_bounds__(256) void bpart_k(
    const int* __restrict__ r0, const int* __restrict__ c0, const float* __restrict__ v0,
    const int* __restrict__ r1, const int* __restrict__ c1, const float* __restrict__ v1,
    const int* __restrict__ r2, const int* __restrict__ c2, const float* __restrict__ v2,
    int* __restrict__ cursor, int2* __restrict__ packed)
{
  __shared__ int hs[256];
  __shared__ int ls[NB3];
  __shared__ int cur[NB3];
  __shared__ int clm[NB3];
  __shared__ int2 stg[CHUNK];
  __shared__ int tgt[CHUNK];
  const int t = threadIdx.x;
  const long long cbase = (long long)blockIdx.x * CHUNK;
  const long long tot = 3LL * N_EDGES;
  hs[t] = 0;
  __syncthreads();
  int rows_[16], gbs_[16];
#pragma unroll
  for (int j = 0; j < 16; ++j) {
    long long idx = cbase + j * 256 + t;
    int gb = -1, row = 0;
    if (idx < tot) {
      int g = (int)(idx / N_EDGES);
      int e = (int)(idx - (long long)g * N_EDGES);
      row = (g == 0 ? r0 : g == 1 ? r1 : r2)[e];
      gb = g * BKT + (row >> 10);
      atomicAdd(&hs[gb], 1);
    }
    gbs_[j] = gb; rows_[j] = row;
  }
  __syncthreads();
  const int myh = hs[t];
  if (t < NB3) clm[t] = atomicAdd(&cursor[t], myh);
  for (int off = 1; off < 256; off <<= 1) {
    int v = (t >= off) ? hs[t - off] : 0;
    __syncthreads();
    hs[t] += v;
    __syncthreads();
  }
  const int excl = hs[t] - myh;
  if (t < NB3) { ls[t] = excl; cur[t] = excl; }
  __syncthreads();
#pragma unroll
  for (int j = 0; j < 16; ++j) {
    const int gb = gbs_[j];
    if (gb >= 0) {
      long long idx = cbase + j * 256 + t;
      int g = (int)(idx / N_EDGES);
      int e = (int)(idx - (long long)g * N_EDGES);
      int col = (g == 0 ? c0 : g == 1 ? c1 : c2)[e];
      float vv = (g == 0 ? v0 : g == 1 ? v1 : v2)[e];
      int slot = atomicAdd(&cur[gb], 1);
      stg[slot] = make_int2(rows_[j] | (col << 16), __float_as_int(vv));
      tgt[slot] = clm[gb] + (slot - ls[gb]);
    }
  }
  __syncthreads();
  const int cnt = (int)min((long long)CHUNK, tot - cbase);
  for (int i = t; i < cnt; i += 256) packed[tgt[i]] = stg[i];
}

__global__ __launch_bounds__(256) void bfinal_k(
    const int2* __restrict__ packed, const int* __restrict__ flatBase,
    int* __restrict__ row_ptr3, int2* __restrict__ cv3)
{
  __shared__ int hist[BROWS];
  __shared__ int part[256];
  const int gb = blockIdx.x;
  const int g = gb / BKT, b = gb % BKT;
  const int rb = b * BROWS;
  const int nrows = min(BROWS, N_NODES - rb);
  const int base = flatBase[gb];
  const int cnt = flatBase[gb + 1] - base;
  const int cvb = base - g * N_EDGES;
  const int t = threadIdx.x;
  for (int i = t; i < BROWS; i += 256) hist[i] = 0;
  __syncthreads();
  for (int i = t; i < cnt; i += 256) {
    int rc = packed[base + i].x;
    atomicAdd(&hist[(rc & 0xffff) - rb], 1);
  }
  __syncthreads();
  const int l0 = hist[4 * t], l1 = hist[4 * t + 1], l2 = hist[4 * t + 2], l3 = hist[4 * t + 3];
  const int s = l0 + l1 + l2 + l3;
  part[t] = s;
  __syncthreads();
  for (int off = 1; off < 256; off <<= 1) {
    int v = (t >= off) ? part[t - off] : 0;
    __syncthreads();
    part[t] += v;
    __syncthreads();
  }
  const int pexcl = part[t] - s;
  const int e0 = pexcl, e1 = e0 + l0, e2 = e1 + l1, e3 = e2 + l2;
  hist[4 * t] = e0; hist[4 * t + 1] = e1; hist[4 * t + 2] = e2; hist[4 * t + 3] = e3;
  int* rp = row_ptr3 + (size_t)g * (N_NODES + 1);
  if (4 * t + 0 < nrows) rp[rb + 4 * t + 0] = cvb + e0;
  if (4 * t + 1 < nrows) rp[rb + 4 * t + 1] = cvb + e1;
  if (4 * t + 2 < nrows) rp[rb + 4 * t + 2] = cvb + e2;
  if (4 * t + 3 < nrows) rp[rb + 4 * t + 3] = cvb + e3;
  if (rb + BROWS >= N_NODES && t == 0) rp[N_NODES] = N_EDGES;
  __syncthreads();
  for (int i = t; i < cnt; i += 256) {
    int2 p = packed[base + i];
    int row = p.x & 0xffff;
    int col = ((unsigned)p.x) >> 16;
    int pos = atomicAdd(&hist[row - rb], 1);
    cv3[base + pos] = make_int2(col, p.y);
  }
}

__global__ void flag_k(const int* __restrict__ ids, unsigned char* __restrict__ flag, int B) {
  int i = blockIdx.x * blockDim.x + threadIdx.x;
  if (i < B) flag[ids[i]] = 1;
}

// ---- spmm inner helper: 8-deep MLP gather loop (bf16 src) ----
__device__ inline void spmm_row(const int2* __restrict__ cv, int e0, int e1,
                                const unsigned short* __restrict__ srcb, int c0,
                                float& a0, float& a1, float& a2, float& a3)
{
  int e = e0;
  for (; e + 7 < e1; e += 8) {
    int2 p[8];
    ushort4 x[8];
#pragma unroll
    for (int j = 0; j < 8; ++j) p[j] = cv[e + j];
#pragma unroll
    for (int j = 0; j < 8; ++j)
      x[j] = *reinterpret_cast<const ushort4*>(srcb + (size_t)p[j].x * D_DIM + c0);
#pragma unroll
    for (int j = 0; j < 8; ++j) {
      const float v = __int_as_float(p[j].y);
      a0 = fmaf(v, bf2f(x[j].x), a0); a1 = fmaf(v, bf2f(x[j].y), a1);
      a2 = fmaf(v, bf2f(x[j].z), a2); a3 = fmaf(v, bf2f(x[j].w), a3);
    }
  }
  for (; e + 3 < e1; e += 4) {
    int2 p[4];
    ushort4 x[4];
#pragma unroll
    for (int j = 0; j < 4; ++j) p[j] = cv[e + j];
#pragma unroll
    for (int j = 0; j < 4; ++j)
      x[j] = *reinterpret_cast<const ushort4*>(srcb + (size_t)p[j].x * D_DIM + c0);
#pragma unroll
    for (int j = 0; j < 4; ++j) {
      const float v = __int_as_float(p[j].y);
      a0 = fmaf(v, bf2f(x[j].x), a0); a1 = fmaf(v, bf2f(x[j].y), a1);
      a2 = fmaf(v, bf2f(x[j].z), a2); a3 = fmaf(v, bf2f(x[j].w), a3);
    }
  }
  for (; e < e1; ++e) {
    int2 p = cv[e];
    float v = __int_as_float(p.y);
    const ushort4 x = *reinterpret_cast<const ushort4*>(srcb + (size_t)p.x * D_DIM + c0);
    a0 = fmaf(v, bf2f(x.x), a0); a1 = fmaf(v, bf2f(x.y), a1);
    a2 = fmaf(v, bf2f(x.z), a2); a3 = fmaf(v, bf2f(x.w), a3);
  }
}

// ---------------- SpMM: bf16 gather, f32 accumulate/out (+opt bf16 shadow) ----
__global__ __launch_bounds__(256) void spmm_k(
    const int* __restrict__ row_ptr, const int2* __restrict__ cv,
    const unsigned short* __restrict__ srcb, float* __restrict__ dst,
    unsigned short* __restrict__ dstb,
    const float* __restrict__ bias, int do_leaky,
    const unsigned char* __restrict__ flag, int n)
{
  int r = (blockIdx.x << 2) + (threadIdx.x >> 6);
  if (r >= n) return;
  if (flag && !flag[r]) return;
  const int lane = threadIdx.x & 63;
  const int c0 = lane << 2;
  int e0 = row_ptr[r], e1 = row_ptr[r + 1];
  float a0 = 0.f, a1 = 0.f, a2 = 0.f, a3 = 0.f;
  spmm_row(cv, e0, e1, srcb, c0, a0, a1, a2, a3);
  if (bias) {
    const float4 b = *reinterpret_cast<const float4*>(bias + c0);
    a0 += b.x; a1 += b.y; a2 += b.z; a3 += b.w;
  }
  if (do_leaky) {
    a0 = a0 > 0.f ? a0 : 0.01f * a0;
    a1 = a1 > 0.f ? a1 : 0.01f * a1;
    a2 = a2 > 0.f ? a2 : 0.01f * a2;
    a3 = a3 > 0.f ? a3 : 0.01f * a3;
  }
  *reinterpret_cast<float4*>(dst + (size_t)r * D_DIM + c0) =
      make_float4(a0, a1, a2, a3);
  if (dstb) {
    ushort4 o;
    o.x = f2bf(a0); o.y = f2bf(a1); o.z = f2bf(a2); o.w = f2bf(a3);
    *reinterpret_cast<ushort4*>(dstb + (size_t)r * D_DIM + c0) = o;
  }
}

// ---- fused rel+attr flagged spmm (z selects graph) ----
struct SP2 {
  const int* rp[2];
  const int2* cv[2];
  const unsigned short* src[2];
  float* dst[2];
  const float* bias[2];
};
__global__ __launch_bounds__(256) void spmm2_k(SP2 a, const unsigned char* __restrict__ flag) {
  const int z = blockIdx.y;
  int r = (blockIdx.x << 2) + (threadIdx.x >> 6);
  if (r >= N_NODES) return;
  if (!flag[r]) return;
  const unsigned short* srcb = a.src[z];
  const int lane = threadIdx.x & 63;
  const int c0 = lane << 2;
  int e0 = a.rp[z][r], e1 = a.rp[z][r + 1];
  const int2* cv = a.cv[z];
  float a0 = 0.f, a1 = 0.f, a2 = 0.f, a3 = 0.f;
  spmm_row(cv, e0, e1, srcb, c0, a0, a1, a2, a3);
  const float4 b = *reinterpret_cast<const float4*>(a.bias[z] + c0);
  a0 += b.x; a1 += b.y; a2 += b.z; a3 += b.w;
  a0 = a0 > 0.f ? a0 : 0.01f * a0;
  a1 = a1 > 0.f ? a1 : 0.01f * a1;
  a2 = a2 > 0.f ? a2 : 0.01f * a2;
  a3 = a3 > 0.f ? a3 : 0.01f * a3;
  *reinterpret_cast<float4*>(a.dst[z] + (size_t)r * D_DIM + c0) =
      make_float4(a0, a1, a2, a3);
}

// ---------------- fused 3-way big GEMM (K=1024, 128x256 tile, bf16-only out) ----
// z==2 (ent): 3-term split-precision. z<2 (rel/attr): 1-term truncated bf16.
// BK=32 (r18 best; BK=64 measured null, r19).
struct MM3 {
  const float* A[3];
  const unsigned short* Wh[3];
  const unsigned short* Wl[3];
  unsigned short* Cb[3];
};
__global__ __launch_bounds__(512, 4) void mm3_k(MM3 a) {
  constexpr int KT = F_DIM;
  const int z = blockIdx.y;
  const bool full = (z == 2);
  const float* __restrict__ Aptr = a.A[z];
  const unsigned short* __restrict__ Wt_hi = a.Wh[z];
  const unsigned short* __restrict__ Wt_lo = a.Wl[z];
  unsigned short* __restrict__ Cb = a.Cb[z];

  __shared__ __align__(16) unsigned char smem[32768];  // hi: [0,16K), lo: [16K,32K)
  const int tid = threadIdx.x;
  const int wid = tid >> 6, lane = tid & 63;
  const int wm = wid & 3, wn = wid >> 2;       // 4 (M) x 2 (N) waves
  const int bm = blockIdx.x * 128;
  const int l15 = lane & 15, lk = lane >> 4;

  int mrow[2];
  const float* arow[2];
#pragma unroll
  for (int mi = 0; mi < 2; ++mi) {
    int m = bm + wm * 32 + mi * 16 + l15;
    mrow[mi] = m;
    arow[mi] = Aptr + (size_t)((m < N_NODES) ? m : 0) * KT;
  }

  const int s1 = tid, s2 = tid + 512;
  const size_t go1 = (size_t)(s1 >> 2) * KT + ((((s1 & 3) - ((s1 >> 3) & 3)) & 3) << 3);
  const size_t go2 = (size_t)(s2 >> 2) * KT + ((((s2 & 3) - ((s2 >> 3) & 3)) & 3) << 3);

  f32x4 acc[2][8] = {};
  for (int kc = 0; kc < KT / 32; ++kc) {
    const int kk = kc * 32;
    __syncthreads();
    glds16(Wt_hi + go1 + kk, smem + s1 * 16);
    glds16(Wt_hi + go2 + kk, smem + s2 * 16);
    if (full) {
      glds16(Wt_lo + go1 + kk, smem + 16384 + s1 * 16);
      glds16(Wt_lo + go2 + kk, smem + 16384 + s2 * 16);
    }
    const int ka = kk + lk * 8;
    bf16x8 ah[2], al[2];
#pragma unroll
    for (int mi = 0; mi < 2; ++mi) {
      uint4 th = {0, 0, 0, 0}, tl = {0, 0, 0, 0};
      if (mrow[mi] < N_NODES) {
        const float* p = arow[mi] + ka;
        const float4 x = *reinterpret_cast<const float4*>(p);
        const float4 y = *reinterpret_cast<const float4*>(p + 4);
        if (full) {
          split_pair(x.x, x.y, th.x, tl.x);
          split_pair(x.z, x.w, th.y, tl.y);
          split_pair(y.x, y.y, th.z, tl.z);
          split_pair(y.z, y.w, th.w, tl.w);
        } else {
          th.x = trunc_pair(x.x, x.y);
          th.y = trunc_pair(x.z, x.w);
          th.z = trunc_pair(y.x, y.y);
          th.w = trunc_pair(y.z, y.w);
        }
      }
      ah[mi] = *reinterpret_cast<bf16x8*>(&th);
      al[mi] = *reinterpret_cast<bf16x8*>(&tl);
    }
    __syncthreads();
#pragma unroll
    for (int f = 0; f < 8; ++f) {
      const int n = wn * 128 + f * 16 + l15;
      const int boff = n * 64 + (((lk + (n >> 1)) & 3) << 4);
      const bf16x8 bh = *reinterpret_cast<const bf16x8*>(smem + boff);
#pragma unroll
      for (int mi = 0; mi < 2; ++mi)
        acc[mi][f] = __builtin_amdgcn_mfma_f32_16x16x32_bf16(ah[mi], bh, acc[mi][f], 0, 0, 0);
      if (full) {
        const bf16x8 bl = *reinterpret_cast<const bf16x8*>(smem + 16384 + boff);
#pragma unroll
        for (int mi = 0; mi < 2; ++mi) {
          acc[mi][f] = __builtin_amdgcn_mfma_f32_16x16x32_bf16(al[mi], bh, acc[mi][f], 0, 0, 0);
          acc[mi][f] = __builtin_amdgcn_mfma_f32_16x16x32_bf16(ah[mi], bl, acc[mi][f], 0, 0, 0);
        }
      }
    }
  }

#pragma unroll
  for (int mi = 0; mi < 2; ++mi) {
    const int rbase = bm + wm * 32 + mi * 16 + lk * 4;
#pragma unroll
    for (int f = 0; f < 8; ++f) {
      const int col = wn * 128 + f * 16 + l15;
#pragma unroll
      for (int r = 0; r < 4; ++r) {
        const int row = rbase + r;
        if (row >= N_NODES) continue;
        Cb[(size_t)row * D_DIM + col] = f2bf(acc[mi][f][r]);
      }
    }
  }
}

// ---------------- col-split MFMA GEMM (64 rows x 128 cols, BK=64) ----------------
// NOT safe for in-place C==A. Used for the ids-GEMMs (lit, nxt3, h3).
// TERMS==1: truncated 1-term bf16 (short error path; lit GEMM only).
template<int KT, int MODE, int TERMS>
__global__ __launch_bounds__(256, 4) void mm_k(
    const float* __restrict__ Aptr,
    const unsigned short* __restrict__ Wt_hi,
    const unsigned short* __restrict__ Wt_lo,
    const float* __restrict__ bias,
    float* __restrict__ C, int ldc, int ccol0, int M,
    const int* __restrict__ rowidx,
    const float* __restrict__ nxt, const float* __restrict__ hin,
    unsigned short* __restrict__ Cb)
{
  __shared__ __align__(16) unsigned char smem[32768];
  const int tid = threadIdx.x;
  const int wid = tid >> 6, lane = tid & 63;
  const int wm = wid & 1, wn = wid >> 1;
  const int bm = blockIdx.y * 64;
  const int bn0 = blockIdx.x * 128;
  const int l15 = lane & 15, lk = lane >> 4;

  int mrow[2];
  const float* arow[2];
#pragma unroll
  for (int mi = 0; mi < 2; ++mi) {
    int m = bm + wm * 32 + mi * 16 + l15;
    mrow[mi] = m;
    int sr = (m < M) ? (rowidx ? rowidx[m] : m) : 0;
    arow[mi] = Aptr + (size_t)sr * KT;
  }

  const int st_n = tid >> 2;
  const int st_seg = ((tid & 3) - ((tid >> 3) & 3)) & 3;
  const size_t goA = (size_t)(bn0 + st_n) * KT + st_seg * 8;
  const size_t goB = goA + (size_t)64 * KT;
  const unsigned ldA = tid * 16, ldB = tid * 16 + 4096;

  f32x4 acc[2][4] = {};
  for (int kc = 0; kc < KT / 64; ++kc) {
    const int kk = kc * 64;
    __syncthreads();
    glds16(Wt_hi + goA + kk,      smem + ldA);
    glds16(Wt_hi + goB + kk,      smem + ldB);
    glds16(Wt_hi + goA + kk + 32, smem + 8192 + ldA);
    glds16(Wt_hi + goB + kk + 32, smem + 8192 + ldB);
    if (TERMS == 3) {
      glds16(Wt_lo + goA + kk,      smem + 16384 + ldA);
      glds16(Wt_lo + goB + kk,      smem + 16384 + ldB);
      glds16(Wt_lo + goA + kk + 32, smem + 24576 + ldA);
      glds16(Wt_lo + goB + kk + 32, smem + 24576 + ldB);
    }
    bf16x8 ah[2][2], al[2][2];
#pragma unroll
    for (int ks = 0; ks < 2; ++ks) {
      const int ka = kk + ks * 32 + lk * 8;
#pragma unroll
      for (int mi = 0; mi < 2; ++mi) {
        uint4 th = {0, 0, 0, 0}, tl = {0, 0, 0, 0};
        if (mrow[mi] < M) {
          const float* p = arow[mi] + ka;
          const float4 x = *reinterpret_cast<const float4*>(p);
          const float4 y = *reinterpret_cast<const float4*>(p + 4);
          if (TERMS == 3) {
            split_pair(x.x, x.y, th.x, tl.x);
            split_pair(x.z, x.w, th.y, tl.y);
            split_pair(y.x, y.y, th.z, tl.z);
            split_pair(y.z, y.w, th.w, tl.w);
          } else {
            th.x = trunc_pair(x.x, x.y);
            th.y = trunc_pair(x.z, x.w);
            th.z = trunc_pair(y.x, y.y);
            th.w = trunc_pair(y.z, y.w);
          }
        }
        ah[ks][mi] = *reinterpret_cast<bf16x8*>(&th);
        al[ks][mi] = *reinterpret_cast<bf16x8*>(&tl);
      }
    }
    __syncthreads();
#pragma unroll
    for (int ks = 0; ks < 2; ++ks) {
#pragma unroll
      for (int f = 0; f < 4; ++f) {
        const int n = wn * 64 + f * 16 + l15;
        const int boff = ks * 8192 + n * 64 + (((lk + (n >> 1)) & 3) << 4);
        const bf16x8 bh = *reinterpret_cast<const bf16x8*>(smem + boff);
#pragma unroll
        for (int mi = 0; mi < 2; ++mi)
          acc[mi][f] = __builtin_amdgcn_mfma_f32_16x16x32_bf16(ah[ks][mi], bh, acc[mi][f], 0, 0, 0);
        if (TERMS == 3) {
          const bf16x8 bl = *reinterpret_cast<const bf16x8*>(smem + 16384 + boff);
#pragma unroll
          for (int mi = 0; mi < 2; ++mi) {
            acc[mi][f] = __builtin_amdgcn_mfma_f32_16x16x32_bf16(al[ks][mi], bh, acc[mi][f], 0, 0, 0);
            acc[mi][f] = __builtin_amdgcn_mfma_f32_16x16x32_bf16(ah[ks][mi], bl, acc[mi][f], 0, 0, 0);
          }
        }
      }
    }
  }

  __syncthreads();

#pragma unroll
  for (int mi = 0; mi < 2; ++mi) {
    const int rbase = bm + wm * 32 + mi * 16 + lk * 4;
    int hsrc[4];
    if (MODE == 2) {
#pragma unroll
      for (int r = 0; r < 4; ++r) {
        const int row = rbase + r;
        hsrc[r] = (rowidx && row < M) ? rowidx[row] : row;
      }
    }
#pragma unroll
    for (int f = 0; f < 4; ++f) {
      const int col = bn0 + wn * 64 + f * 16 + l15;
      const float bc = bias ? bias[col] : 0.f;
#pragma unroll
      for (int r = 0; r < 4; ++r) {
        const int row = rbase + r;
        if (row >= M) continue;
        float v = acc[mi][f][r] + bc;
        if (MODE == 1) v = v > 0.f ? v : 0.01f * v;
        if (MODE == 2) {
          const float g = 1.f / (1.f + __expf(-v));
          const float nv = nxt[(size_t)row * D_DIM + col];
          const float hv = hin[(size_t)hsrc[r] * D_DIM + col];
          v = g * nv + (1.f - g) * hv;
        }
        C[(size_t)row * ldc + ccol0 + col] = v;
        if (Cb) Cb[(size_t)row * D_DIM + col] = f2bf(v);
      }
    }
  }
}

// ---------------- full-width MFMA GEMM (128 rows x 256 cols, 512 thr) -------
// Safe for in-place C==A. Used for the two in-place D-GEMMs (nxt2, h2).
template<int KT, int MODE>
__global__ __launch_bounds__(512, 4) void mmw_k(
    const float* __restrict__ Aptr,
    const unsigned short* __restrict__ Wt_hi,
    const unsigned short* __restrict__ Wt_lo,
    const float* __restrict__ bias,
    float* __restrict__ C, int ldc, int ccol0, int M,
    const int* __restrict__ rowidx,
    const float* __restrict__ nxt, const float* __restrict__ hin,
    unsigned short* __restrict__ Cb)
{
  __shared__ __align__(16) unsigned char smem[32768];
  const int tid = threadIdx.x;
  const int wid = tid >> 6, lane = tid & 63;
  const int wm = wid & 3, wn = wid >> 2;
  const int bm = blockIdx.x * 128;
  const int l15 = lane & 15, lk = lane >> 4;

  int mrow[2];
  const float* arow[2];
#pragma unroll
  for (int mi = 0; mi < 2; ++mi) {
    int m = bm + wm * 32 + mi * 16 + l15;
    mrow[mi] = m;
    int sr = (m < M) ? (rowidx ? rowidx[m] : m) : 0;
    arow[mi] = Aptr + (size_t)sr * KT;
  }

  const int s1 = tid, s2 = tid + 512;
  const size_t go1 = (size_t)(s1 >> 2) * KT + ((((s1 & 3) - ((s1 >> 3) & 3)) & 3) << 3);
  const size_t go2 = (size_t)(s2 >> 2) * KT + ((((s2 & 3) - ((s2 >> 3) & 3)) & 3) << 3);

  f32x4 acc[2][8] = {};
  for (int kc = 0; kc < KT / 32; ++kc) {
    const int kk = kc * 32;
    __syncthreads();
    glds16(Wt_hi + go1 + kk, smem + s1 * 16);
    glds16(Wt_hi + go2 + kk, smem + s2 * 16);
    glds16(Wt_lo + go1 + kk, smem + 16384 + s1 * 16);
    glds16(Wt_lo + go2 + kk, smem + 16384 + s2 * 16);
    const int ka = kk + lk * 8;
    bf16x8 ah[2], al[2];
#pragma unroll
    for (int mi = 0; mi < 2; ++mi) {
      uint4 th = {0, 0, 0, 0}, tl = {0, 0, 0, 0};
      if (mrow[mi] < M) {
        const float* p = arow[mi] + ka;
        const float4 x = *reinterpret_cast<const float4*>(p);
        const float4 y = *reinterpret_cast<const float4*>(p + 4);
        split_pair(x.x, x.y, th.x, tl.x);
        split_pair(x.z, x.w, th.y, tl.y);
        split_pair(y.x, y.y, th.z, tl.z);
        split_pair(y.z, y.w, th.w, tl.w);
      }
      ah[mi] = *reinterpret_cast<bf16x8*>(&th);
      al[mi] = *reinterpret_cast<bf16x8*>(&tl);
    }
    __syncthreads();
#pragma unroll
    for (int f = 0; f < 8; ++f) {
      const int n = wn * 128 + f * 16 + l15;
      const int boff = n * 64 + (((lk + (n >> 1)) & 3) << 4);
      const bf16x8 bh = *reinterpret_cast<const bf16x8*>(smem + boff);
      const bf16x8 bl = *reinterpret_cast<const bf16x8*>(smem + 16384 + boff);
#pragma unroll
      for (int mi = 0; mi < 2; ++mi) {
        acc[mi][f] = __builtin_amdgcn_mfma_f32_16x16x32_bf16(ah[mi], bh, acc[mi][f], 0, 0, 0);
        acc[mi][f] = __builtin_amdgcn_mfma_f32_16x16x32_bf16(al[mi], bh, acc[mi][f], 0, 0, 0);
        acc[mi][f] = __builtin_amdgcn_mfma_f32_16x16x32_bf16(ah[mi], bl, acc[mi][f], 0, 0, 0);
      }
    }
  }

  __syncthreads();   // in-place safety: all A reads in block done before writes

#pragma unroll
  for (int mi = 0; mi < 2; ++mi) {
    const int rbase = bm + wm * 32 + mi * 16 + lk * 4;
    int hsrc[4];
    if (MODE == 2) {
#pragma unroll
      for (int r = 0; r < 4; ++r) {
        const int row = rbase + r;
        hsrc[r] = (rowidx && row < M) ? rowidx[row] : row;
      }
    }
#pragma unroll
    for (int f = 0; f < 8; ++f) {
      const int col = wn * 128 + f * 16 + l15;
      const float bc = bias ? bias[col] : 0.f;
#pragma unroll
      for (int r = 0; r < 4; ++r) {
        const int row = rbase + r;
        if (row >= M) continue;
        float v = acc[mi][f][r] + bc;
        if (MODE == 1) v = v > 0.f ? v : 0.01f * v;
        if (MODE == 2) {
          const float g = 1.f / (1.f + __expf(-v));
          const float nv = nxt[(size_t)row * D_DIM + col];
          const float hv = hin[(size_t)hsrc[r] * D_DIM + col];
          v = g * nv + (1.f - g) * hv;
        }
        C[(size_t)row * ldc + ccol0 + col] = v;
        if (Cb) Cb[(size_t)row * D_DIM + col] = f2bf(v);
      }
    }
  }
}

// ---------------- row gathers ----------------
struct GA2 { const float* src[2]; int col0[2]; };
__global__ __launch_bounds__(256) void gather2_k(GA2 a, const int* __restrict__ ids,
                                                 float* __restrict__ dst)
{
  const int z = blockIdx.y;
  int i = (blockIdx.x << 2) + (threadIdx.x >> 6);
  if (i >= B_IDS) return;
  const int lane = threadIdx.x & 63;
  const int c0 = lane << 2;
  const float4 v = *reinterpret_cast<const float4*>(a.src[z] + (size_t)ids[i] * D_DIM + c0);
  *reinterpret_cast<float4*>(dst + (size_t)i * 1024 + a.col0[z] + c0) = v;
}

// ---------------- launch ----------------
extern "C" void kernel_launch(void* const* d_in, const int* in_sizes, int n_in,
                              void* d_out, int out_size, void* d_ws, size_t ws_size,
                              hipStream_t stream)
{
  const float* ent_lit = (const float*)d_in[0];
  const float* rel_lit = (const float*)d_in[1];
  const float* attr_lit = (const float*)d_in[2];
  const float* ent_val = (const float*)d_in[3];
  const float* rel_val = (const float*)d_in[4];
  const float* attr_val = (const float*)d_in[5];
  const float* W_ent = (const float*)d_in[6];
  const float* b_ent = (const float*)d_in[7];
  const float* W_rel = (const float*)d_in[8];
  const float* b_rel = (const float*)d_in[9];
  const float* W_attr = (const float*)d_in[10];
  const float* b_attr = (const float*)d_in[11];
  const float* W_x = (const float*)d_in[12];
  const float* b_x = (const float*)d_in[13];
  const float* W_lit = (const float*)d_in[14];
  const float* b_lit = (const float*)d_in[15];
  const float* W_gate = (const float*)d_in[16];
  const float* b_gate = (const float*)d_in[17];
  const int* ent_row = (const int*)d_in[18];
  const int* ent_col = (const int*)d_in[19];
  const int* rel_row = (const int*)d_in[20];
  const int* rel_col = (const int*)d_in[21];
  const int* attr_row = (const int*)d_in[22];
  const int* attr_col = (const int*)d_in[23];
  const int* ent_ids = (const int*)d_in[24];
  float* out = (float*)d_out;

  char* p = (char*)d_ws;
  const size_t bufsz = alignup((size_t)N_NODES * D_DIM * 4);
  const size_t bufszb = alignup((size_t)N_NODES * D_DIM * 2);
  const size_t wsz_f = alignup((size_t)F_DIM * D_DIM * 2);
  const size_t wsz_d = alignup((size_t)D_DIM * D_DIM * 2);
  float* B0 = (float*)p; p += bufsz;
  float* B1 = (float*)p; p += bufsz;
  unsigned short* Bb0 = (unsigned short*)p; p += bufszb;  // rel GEMM out -> h1 shadow
  unsigned short* Bb1 = (unsigned short*)p; p += bufszb;  // attr GEMM out -> h2 shadow
  unsigned short* Bb2 = (unsigned short*)p; p += bufszb;  // ent GEMM out -> (aliased by P)
  float* P = (float*)Bb2;  // Bb2 dead after h1 spmm; P (16.8MB) fits in Bb2 (25.6MB)
  unsigned short* Wh_ent = (unsigned short*)p; p += wsz_f;
  unsigned short* Wl_ent = (unsigned short*)p; p += wsz_f;
  unsigned short* Wh_rel = (unsigned short*)p; p += wsz_f;
  unsigned short* Wl_rel = (unsigned short*)p; p += wsz_f;
  unsigned short* Wh_attr = (unsigned short*)p; p += wsz_f;
  unsigned short* Wl_attr = (unsigned short*)p; p += wsz_f;
  unsigned short* Wh_lit = (unsigned short*)p; p += wsz_f;
  unsigned short* Wl_lit = (unsigned short*)p; p += wsz_f;
  unsigned short* Wh_x = (unsigned short*)p; p += wsz_d;
  unsigned short* Wl_x = (unsigned short*)p; p += wsz_d;
  unsigned short* Wh_gate = (unsigned short*)p; p += wsz_d;
  unsigned short* Wl_gate = (unsigned short*)p; p += wsz_d;
  int* row_ptr3 = (int*)p; p += alignup((size_t)3 * (N_NODES + 1) * 4);
  int* bcnt = (int*)p; p += alignup((size_t)NB3 * 4);
  int* flatBase = (int*)p; p += alignup((size_t)(NB3 + 1) * 4);
  int* cursor = (int*)p; p += alignup((size_t)NB3 * 4);
  unsigned char* flags = (unsigned char*)p; p += alignup((size_t)N_NODES);
  int2* cv3 = (int2*)p; p += alignup((size_t)3 * N_EDGES * 8);
  if ((size_t)(p - (char*)d_ws) > ws_size) return;

  // packed edge buffer aliases B0 (first real write to B0 is after bfinal)
  int2* packed = (int2*)B0;

  const int* rp_ent = row_ptr3;
  const int* rp_rel = row_ptr3 + (N_NODES + 1);
  const int* rp_attr = row_ptr3 + 2 * (N_NODES + 1);
  const int2* cv_ent = cv3;
  const int2* cv_rel = cv3 + (size_t)N_EDGES;
  const int2* cv_attr = cv3 + (size_t)2 * N_EDGES;

  dim3 blk(256), blk512(512);
  const int nchunks = (int)((3LL * N_EDGES + CHUNK - 1) / CHUNK);
  dim3 g_spmm((N_NODES + 3) / 4);
  dim3 g_spmm2((N_NODES + 3) / 4, 2);
  dim3 g_gather2((B_IDS + 3) / 4, 2);
  dim3 g_mm3((N_NODES + 127) / 128, 3);
  dim3 g_mm_ids(2, B_IDS / 64);
  dim3 g_mmw_big((N_NODES + 127) / 128);

  // weights -> bf16 hi/lo transposed (one fused launch)
  TrArgs ta;
  ta.W[0] = W_ent;  ta.Wh[0] = Wh_ent;  ta.Wl[0] = Wl_ent;  ta.K[0] = F_DIM;
  ta.W[1] = W_rel;  ta.Wh[1] = Wh_rel;  ta.Wl[1] = Wl_rel;  ta.K[1] = F_DIM;
  ta.W[2] = W_attr; ta.Wh[2] = Wh_attr; ta.Wl[2] = Wl_attr; ta.K[2] = F_DIM;
  ta.W[3] = W_lit;  ta.Wh[3] = Wh_lit;  ta.Wl[3] = Wl_lit;  ta.K[3] = F_DIM;
  ta.W[4] = W_x;    ta.Wh[4] = Wh_x;    ta.Wl[4] = Wl_x;    ta.K[4] = D_DIM;
  ta.W[5] = W_gate; ta.Wh[5] = Wh_gate; ta.Wl[5] = Wl_gate; ta.K[5] = D_DIM;
  tr_all_k<<<dim3(F_DIM / 64, 4, 6), blk, 0, stream>>>(ta);

  // CSR build (bucket sort)
  hipMemsetAsync(bcnt, 0, NB3 * sizeof(int), stream);
  bcount_k<<<dim3(nchunks), blk, 0, stream>>>(ent_row, rel_row, attr_row, bcnt);
  bscan_k<<<dim3(1), blk, 0, stream>>>(bcnt, flatBase, cursor);
  bpart_k<<<dim3(nchunks), blk, 0, stream>>>(ent_row, ent_col, ent_val,
                                             rel_row, rel_col, rel_val,
                                             attr_row, attr_col, attr_val,
                                             cursor, packed);
  bfinal_k<<<dim3(NB3), blk, 0, stream>>>(packed, flatBase, row_ptr3, cv3);

  // flags for row restriction (rows observed via ent_ids)
  hipMemsetAsync(flags, 0, N_NODES, stream);
  flag_k<<<dim3(B_IDS / 256), blk, 0, stream>>>(ent_ids, flags, B_IDS);

  // ----- fused big GEMMs: Bb0 = rel_lit@W_rel, Bb1 = attr_lit@W_attr, Bb2 = ent_lit@W_ent
  MM3 m3;
  m3.A[0] = rel_lit;  m3.Wh[0] = Wh_rel;  m3.Wl[0] = Wl_rel;  m3.Cb[0] = Bb0;
  m3.A[1] = attr_lit; m3.Wh[1] = Wh_attr; m3.Wl[1] = Wl_attr; m3.Cb[1] = Bb1;
  m3.A[2] = ent_lit;  m3.Wh[2] = Wh_ent;  m3.Wl[2] = Wl_ent;  m3.Cb[2] = Bb2;
  mm3_k<<<g_mm3, blk512, 0, stream>>>(m3);

  // ----- fused rel+attr flagged spmm: rel->B1, attr->B0
  SP2 s2;
  s2.rp[0] = rp_rel;  s2.cv[0] = cv_rel;  s2.src[0] = Bb0; s2.dst[0] = B1; s2.bias[0] = b_rel;
  s2.rp[1] = rp_attr; s2.cv[1] = cv_attr; s2.src[1] = Bb1; s2.dst[1] = B0; s2.bias[1] = b_attr;
  spmm2_k<<<g_spmm2, blk, 0, stream>>>(s2, flags);

  // ----- fused gathers: B1 -> out[:,512:768], B0 -> out[:,768:1024]
  GA2 ga;
  ga.src[0] = B1; ga.col0[0] = 512;
  ga.src[1] = B0; ga.col0[1] = 768;
  gather2_k<<<g_gather2, blk, 0, stream>>>(ga, ent_ids, out);

  // ----- ent literals -> out[:,0:256]  (1-term: shortest error path)
  mm_k<F_DIM, 0, 1><<<g_mm_ids, blk, 0, stream>>>(ent_lit, Wh_lit, Wl_lit, b_lit, out, 1024, 0,
                                                  B_IDS, ent_ids, nullptr, nullptr, nullptr);

  // ----- ent n-hop -----
  // h1 = leaky(spmm(Bb2) + b_ent): f32 -> B1, bf16 shadow -> Bb0 (rel shadow dead)
  spmm_k<<<g_spmm, blk, 0, stream>>>(rp_ent, cv_ent, Bb2, B1, Bb0, b_ent, 1, nullptr, N_NODES);
  // hop 2: s2 = spmm(h1 shadow) -> B0 (f32 only)
  spmm_k<<<g_spmm, blk, 0, stream>>>(rp_ent, cv_ent, Bb0, B0, nullptr, nullptr, 0, nullptr, N_NODES);
  // in-place D-GEMMs use the full-width kernel
  mmw_k<D_DIM, 1><<<g_mmw_big, blk512, 0, stream>>>(B0, Wh_x, Wl_x, b_x, B0, D_DIM, 0,
                                                    N_NODES, nullptr, nullptr, nullptr, nullptr); // nxt2=B0
  mmw_k<D_DIM, 2><<<g_mmw_big, blk512, 0, stream>>>(B1, Wh_gate, Wl_gate, b_gate, B1, D_DIM, 0,
                                                    N_NODES, nullptr, B0, B1, Bb1);               // h2=B1(+Bb1)
  // hop 3 (flagged): s3 = spmm(h2 shadow) -> B0
  spmm_k<<<g_spmm, blk, 0, stream>>>(rp_ent, cv_ent, Bb1, B0, nullptr, nullptr, 0, flags, N_NODES);
  mm_k<D_DIM, 1, 3><<<g_mm_ids, blk, 0, stream>>>(B0, Wh_x, Wl_x, b_x, P, D_DIM, 0,
                                                  B_IDS, ent_ids, nullptr, nullptr, nullptr);   // nxt3 (P aliases Bb2)
  mm_k<D_DIM, 2, 3><<<g_mm_ids, blk, 0, stream>>>(B1, Wh_gate, Wl_gate, b_gate, out, 1024, 256,
                                                  B_IDS, ent_ids, P, B1, nullptr);              // -> out[:,256:512]
}